// Round 1
// baseline (111.865 us; speedup 1.0000x reference)
//
#include <hip/hip_runtime.h>

#define BATCH 8
#define NTOK 4096
#define CH 256
#define IMG 1024
#define PATCH 16
#define CHUNKS 64                 // blocks per (batch, input)
#define TOK_PER_BLK (NTOK / CHUNKS)  // 64 tokens per block

// Workspace float layout:
//   [0,     2048)  pos_num[b][c]   = sum_n ep_m * ep_e
//   [2048,  4096)  sum_e [b][c]    = sum_n ep_e
//   [4096,  6144)  u     [b][c]    = sum_n q_m * q_e
//   [6144,  8192)  v     [b][c]    = sum_n q_e
//   [8192,  8200)  cnt_ep[b]       = sum_n ep_m
//   [8200,  8208)  A[b]            = sum_n q_m * ||q_n||^2
//   [8208,  8216)  Bq[b]           = sum_n ||q_n||^2
//   [8216,  8224)  npos[b]         = sum_n q_m
#define WS_FLOATS 8224

__device__ __forceinline__ float wave_reduce_sum(float v) {
    for (int off = 32; off > 0; off >>= 1) v += __shfl_down(v, off, 64);
    return v;
}

__global__ __launch_bounds__(256) void stats_kernel(
    const float* __restrict__ ep_e, const float* __restrict__ ep_m,
    const float* __restrict__ q_e,  const float* __restrict__ q_m,
    float* __restrict__ ws)
{
    const int bid  = blockIdx.x;
    const bool is_q = (bid >= BATCH * CHUNKS);
    const int lb   = bid & (BATCH * CHUNKS - 1);
    const int b    = lb / CHUNKS;
    const int start = (lb % CHUNKS) * TOK_PER_BLK;

    const float* __restrict__ embed = is_q ? q_e : ep_e;
    const float* __restrict__ mask  = is_q ? q_m : ep_m;

    const int tid  = threadIdx.x;
    const int w    = tid >> 6;      // wave 0..3 -> token subphase
    const int lane = tid & 63;
    const int cbase = lane << 2;    // 4 channels per lane

    float4 accW = {0.f, 0.f, 0.f, 0.f};   // sum m*e  (pos_num or u)
    float4 accS = {0.f, 0.f, 0.f, 0.f};   // sum e    (sum_e or v)
    float accA = 0.f, accBv = 0.f, accm = 0.f;

    for (int n0 = start; n0 < start + TOK_PER_BLK; n0 += 4) {
        const int n = n0 + w;                 // this wave's token
        const int i = n >> 6, j = n & 63;
        const float m = mask[(size_t)(b * IMG + i * PATCH) * IMG + (size_t)(j * PATCH)];
        const float4 e = *reinterpret_cast<const float4*>(
            embed + ((size_t)(b * NTOK + n) * CH) + cbase);
        accW.x += m * e.x; accW.y += m * e.y; accW.z += m * e.z; accW.w += m * e.w;
        accS.x += e.x;     accS.y += e.y;     accS.z += e.z;     accS.w += e.w;
        if (is_q) {
            const float d = e.x * e.x + e.y * e.y + e.z * e.z + e.w * e.w;
            accA  += m * d;
            accBv += d;
        }
        accm += m;   // wave-uniform; only lane 0's copy is used
    }

    float* wdst = ws + (is_q ? 4096 : 0);     // u     : pos_num
    float* sdst = ws + (is_q ? 6144 : 2048);  // v     : sum_e
    const int co = b * CH + cbase;
    atomicAdd(&wdst[co + 0], accW.x);
    atomicAdd(&wdst[co + 1], accW.y);
    atomicAdd(&wdst[co + 2], accW.z);
    atomicAdd(&wdst[co + 3], accW.w);
    atomicAdd(&sdst[co + 0], accS.x);
    atomicAdd(&sdst[co + 1], accS.y);
    atomicAdd(&sdst[co + 2], accS.z);
    atomicAdd(&sdst[co + 3], accS.w);

    if (is_q) {
        accA  = wave_reduce_sum(accA);
        accBv = wave_reduce_sum(accBv);
        if (lane == 0) {
            atomicAdd(&ws[8200 + b], accA);
            atomicAdd(&ws[8208 + b], accBv);
            atomicAdd(&ws[8216 + b], accm);
        }
    } else {
        if (lane == 0) {
            atomicAdd(&ws[8192 + b], accm);
        }
    }
}

__global__ __launch_bounds__(256) void finalize_kernel(
    const float* __restrict__ ws, float* __restrict__ out)
{
    __shared__ float4 red[256];
    const int c = threadIdx.x;
    float sum_pos = 0.f, sum_neg = 0.f;   // only thread 0 accumulates

    for (int b = 0; b < BATCH; ++b) {
        const float cnt = ws[8192 + b];
        const float pn  = ws[b * CH + c];
        const float se  = ws[2048 + b * CH + c];
        const float pc  = pn / (cnt + 0.1f);
        const float nc  = (se - pn) / (((float)NTOK - cnt) + 0.1f);
        const float uu  = ws[4096 + b * CH + c];
        const float vv  = ws[6144 + b * CH + c];

        float4 t;
        t.x = uu * pc;          // u . p
        t.y = (vv - uu) * nc;   // (v-u) . n
        t.z = pc * pc;          // ||p||^2
        t.w = nc * nc;          // ||n||^2
        red[c] = t;
        __syncthreads();
        for (int s = 128; s > 0; s >>= 1) {
            if (c < s) {
                red[c].x += red[c + s].x;
                red[c].y += red[c + s].y;
                red[c].z += red[c + s].z;
                red[c].w += red[c + s].w;
            }
            __syncthreads();
        }

        if (c == 0) {
            const float A  = ws[8200 + b];
            const float Bv = ws[8208 + b];
            const float np = ws[8216 + b];
            const float nn = (float)NTOK - np;
            const float pos_term = A - 2.f * red[0].x + np * red[0].z;
            const float neg_term = (Bv - A) - 2.f * red[0].y + nn * red[0].w;
            const float pos_loss = (np > 0.f) ? pos_term / (fmaxf(np, 1.f) * (float)CH) : 0.f;
            const float neg_loss = (nn > 0.f) ? neg_term / (fmaxf(nn, 1.f) * (float)CH) : 0.f;
            sum_pos += pos_loss;
            sum_neg += neg_loss;
        }
        __syncthreads();
    }

    if (c == 0) {
        out[0] = (sum_pos + sum_neg) / (float)BATCH;  // mean(center_loss)
        out[1] = sum_pos / (float)BATCH;              // mean(pos_loss)
        out[2] = sum_neg / (float)BATCH;              // mean(neg_loss)
    }
}

extern "C" void kernel_launch(void* const* d_in, const int* in_sizes, int n_in,
                              void* d_out, int out_size, void* d_ws, size_t ws_size,
                              hipStream_t stream) {
    const float* ep_e = (const float*)d_in[0];  // ep_mask_embed (8,4096,256)
    const float* ep_m = (const float*)d_in[1];  // ep_mask (8,1,1024,1024)
    const float* q_e  = (const float*)d_in[2];  // query_mask_embed
    const float* q_m  = (const float*)d_in[3];  // query_mask
    float* out = (float*)d_out;
    float* ws  = (float*)d_ws;

    hipMemsetAsync(ws, 0, WS_FLOATS * sizeof(float), stream);
    stats_kernel<<<2 * BATCH * CHUNKS, 256, 0, stream>>>(ep_e, ep_m, q_e, q_m, ws);
    finalize_kernel<<<1, 256, 0, stream>>>(ws, out);
}

// Round 2
// 42.637 us; speedup vs baseline: 2.6237x; 2.6237x over previous
//
#include <hip/hip_runtime.h>

#define BATCH 8
#define NTOK 4096
#define CH 256
#define IMG 1024
#define PATCH 16
#define CHUNKS 32                    // blocks per (batch, input)
#define TOK_PER_BLK (NTOK / CHUNKS)  // 128 tokens per block

// Workspace float layout:
//   [0,     2048)  pos_num[b][c]   = sum_n ep_m * ep_e
//   [2048,  4096)  sum_e [b][c]    = sum_n ep_e
//   [4096,  6144)  u     [b][c]    = sum_n q_m * q_e
//   [6144,  8192)  v     [b][c]    = sum_n q_e
//   [8192,  8200)  cnt_ep[b]       = sum_n ep_m
//   [8200,  8208)  A[b]            = sum_n q_m * ||q_n||^2
//   [8208,  8216)  Bq[b]           = sum_n ||q_n||^2
//   [8216,  8224)  npos[b]         = sum_n q_m
#define WS_FLOATS 8224

__device__ __forceinline__ float wave_reduce_sum(float v) {
    for (int off = 32; off > 0; off >>= 1) v += __shfl_down(v, off, 64);
    return v;
}

__global__ __launch_bounds__(256) void stats_kernel(
    const float* __restrict__ ep_e, const float* __restrict__ ep_m,
    const float* __restrict__ q_e,  const float* __restrict__ q_m,
    float* __restrict__ ws)
{
    const int bid  = blockIdx.x;
    const bool is_q = (bid >= BATCH * CHUNKS);
    const int lb   = bid & (BATCH * CHUNKS - 1);
    const int b    = lb / CHUNKS;
    const int start = (lb % CHUNKS) * TOK_PER_BLK;

    const float* __restrict__ embed = is_q ? q_e : ep_e;
    const float* __restrict__ mask  = is_q ? q_m : ep_m;

    const int tid  = threadIdx.x;
    const int w    = tid >> 6;      // wave 0..3
    const int lane = tid & 63;
    const int cbase = lane << 2;    // 4 channels per lane

    float4 accW = {0.f, 0.f, 0.f, 0.f};   // sum m*e  (pos_num or u)
    float4 accS = {0.f, 0.f, 0.f, 0.f};   // sum e    (sum_e or v)
    float accA = 0.f, accBv = 0.f, accm = 0.f;

    #pragma unroll 8
    for (int n0 = start; n0 < start + TOK_PER_BLK; n0 += 4) {
        const int n = n0 + w;                 // this wave's token
        const int i = n >> 6, j = n & 63;
        const float m = mask[(size_t)(b * IMG + i * PATCH) * IMG + (size_t)(j * PATCH)];
        const float4 e = *reinterpret_cast<const float4*>(
            embed + ((size_t)(b * NTOK + n) * CH) + cbase);
        accW.x += m * e.x; accW.y += m * e.y; accW.z += m * e.z; accW.w += m * e.w;
        accS.x += e.x;     accS.y += e.y;     accS.z += e.z;     accS.w += e.w;
        if (is_q) {
            const float d = e.x * e.x + e.y * e.y + e.z * e.z + e.w * e.w;
            accA  += m * d;
            accBv += d;
        }
        accm += m;   // wave-uniform
    }

    // ---- LDS reduce across the 4 waves (same 256 channels each) ----
    __shared__ __align__(16) float ldsW[4][CH];
    __shared__ __align__(16) float ldsS[4][CH];
    __shared__ float ldsA[4], ldsB[4], ldsM[4];

    *reinterpret_cast<float4*>(&ldsW[w][cbase]) = accW;
    *reinterpret_cast<float4*>(&ldsS[w][cbase]) = accS;
    if (is_q) {
        accA  = wave_reduce_sum(accA);
        accBv = wave_reduce_sum(accBv);
    }
    if (lane == 0) { ldsA[w] = accA; ldsB[w] = accBv; ldsM[w] = accm; }
    __syncthreads();

    const int c = tid;  // 0..255: one channel per thread
    const float sumW = ldsW[0][c] + ldsW[1][c] + ldsW[2][c] + ldsW[3][c];
    const float sumS = ldsS[0][c] + ldsS[1][c] + ldsS[2][c] + ldsS[3][c];

    float* wdst = ws + (is_q ? 4096 : 0);     // u     : pos_num
    float* sdst = ws + (is_q ? 6144 : 2048);  // v     : sum_e
    atomicAdd(&wdst[b * CH + c], sumW);
    atomicAdd(&sdst[b * CH + c], sumS);

    if (tid == 0) {
        const float sm = ldsM[0] + ldsM[1] + ldsM[2] + ldsM[3];
        if (is_q) {
            atomicAdd(&ws[8200 + b], ldsA[0] + ldsA[1] + ldsA[2] + ldsA[3]);
            atomicAdd(&ws[8208 + b], ldsB[0] + ldsB[1] + ldsB[2] + ldsB[3]);
            atomicAdd(&ws[8216 + b], sm);
        } else {
            atomicAdd(&ws[8192 + b], sm);
        }
    }
}

__global__ __launch_bounds__(256) void finalize_kernel(
    const float* __restrict__ ws, float* __restrict__ out)
{
    __shared__ float4 red[256];
    const int c = threadIdx.x;
    float sum_pos = 0.f, sum_neg = 0.f;   // only thread 0 accumulates

    for (int b = 0; b < BATCH; ++b) {
        const float cnt = ws[8192 + b];
        const float pn  = ws[b * CH + c];
        const float se  = ws[2048 + b * CH + c];
        const float pc  = pn / (cnt + 0.1f);
        const float nc  = (se - pn) / (((float)NTOK - cnt) + 0.1f);
        const float uu  = ws[4096 + b * CH + c];
        const float vv  = ws[6144 + b * CH + c];

        float4 t;
        t.x = uu * pc;          // u . p
        t.y = (vv - uu) * nc;   // (v-u) . n
        t.z = pc * pc;          // ||p||^2
        t.w = nc * nc;          // ||n||^2
        red[c] = t;
        __syncthreads();
        for (int s = 128; s > 0; s >>= 1) {
            if (c < s) {
                red[c].x += red[c + s].x;
                red[c].y += red[c + s].y;
                red[c].z += red[c + s].z;
                red[c].w += red[c + s].w;
            }
            __syncthreads();
        }

        if (c == 0) {
            const float A  = ws[8200 + b];
            const float Bv = ws[8208 + b];
            const float np = ws[8216 + b];
            const float nn = (float)NTOK - np;
            const float pos_term = A - 2.f * red[0].x + np * red[0].z;
            const float neg_term = (Bv - A) - 2.f * red[0].y + nn * red[0].w;
            const float pos_loss = (np > 0.f) ? pos_term / (fmaxf(np, 1.f) * (float)CH) : 0.f;
            const float neg_loss = (nn > 0.f) ? neg_term / (fmaxf(nn, 1.f) * (float)CH) : 0.f;
            sum_pos += pos_loss;
            sum_neg += neg_loss;
        }
        __syncthreads();
    }

    if (c == 0) {
        out[0] = (sum_pos + sum_neg) / (float)BATCH;  // mean(center_loss)
        out[1] = sum_pos / (float)BATCH;              // mean(pos_loss)
        out[2] = sum_neg / (float)BATCH;              // mean(neg_loss)
    }
}

extern "C" void kernel_launch(void* const* d_in, const int* in_sizes, int n_in,
                              void* d_out, int out_size, void* d_ws, size_t ws_size,
                              hipStream_t stream) {
    const float* ep_e = (const float*)d_in[0];  // ep_mask_embed (8,4096,256)
    const float* ep_m = (const float*)d_in[1];  // ep_mask (8,1,1024,1024)
    const float* q_e  = (const float*)d_in[2];  // query_mask_embed
    const float* q_m  = (const float*)d_in[3];  // query_mask
    float* out = (float*)d_out;
    float* ws  = (float*)d_ws;

    hipMemsetAsync(ws, 0, WS_FLOATS * sizeof(float), stream);
    stats_kernel<<<2 * BATCH * CHUNKS, 256, 0, stream>>>(ep_e, ep_m, q_e, q_m, ws);
    finalize_kernel<<<1, 256, 0, stream>>>(ws, out);
}

// Round 3
// 22.609 us; speedup vs baseline: 4.9479x; 1.8859x over previous
//
#include <hip/hip_runtime.h>

#define BATCH 8
#define NTOK 4096
#define CH 256
#define IMG 1024
#define PATCH 16
#define CHUNKS 32                    // blocks per (batch, input)
#define TPB (NTOK / CHUNKS)          // 128 tokens per block
#define PART_STRIDE 520              // per-block partial: 256 W + 256 S + scalars
#define NBLK_STATS (2 * BATCH * CHUNKS)  // 512

// ws layout: block bid (= is_q*256 + b*32 + chunk) owns floats
//   [bid*520 + 0,   256)  W[c] = sum_n m * e      (pos_num or u)
//   [bid*520 + 256, 512)  S[c] = sum_n e          (sum_e or v)
//   [bid*520 + 512]       sum_n m
//   [bid*520 + 513]       sum_n m*||e||^2  (q only, else 0)
//   [bid*520 + 514]       sum_n ||e||^2    (q only, else 0)

__device__ __forceinline__ float wave_reduce_sum(float v) {
    for (int off = 32; off > 0; off >>= 1) v += __shfl_down(v, off, 64);
    return v;
}

__global__ __launch_bounds__(256) void stats_kernel(
    const float* __restrict__ ep_e, const float* __restrict__ ep_m,
    const float* __restrict__ q_e,  const float* __restrict__ q_m,
    float* __restrict__ ws, float* __restrict__ out)
{
    const int bid = blockIdx.x;
    const int tid = threadIdx.x;
    if (bid == 0 && tid < 3) out[tid] = 0.f;   // finalize accumulates into out

    const bool is_q = (bid >= BATCH * CHUNKS);
    const int lb    = bid & (BATCH * CHUNKS - 1);
    const int b     = lb >> 5;                  // /CHUNKS
    const int start = (lb & (CHUNKS - 1)) * TPB;

    const float* __restrict__ embed = is_q ? q_e : ep_e;
    const float* __restrict__ mask  = is_q ? q_m : ep_m;

    const int w = tid >> 6, lane = tid & 63, cbase = lane << 2;

    float4 accW = {0.f, 0.f, 0.f, 0.f};
    float4 accS = {0.f, 0.f, 0.f, 0.f};
    float accA = 0.f, accB = 0.f, accm = 0.f;

    const float* ebase = embed + (size_t)(b * NTOK + start) * CH + cbase;
    const size_t mbase = (size_t)b * IMG * IMG;

    #pragma unroll 16
    for (int t = w; t < TPB; t += 4) {
        const int n = start + t;
        const float m = mask[mbase + (size_t)((n >> 6) * PATCH) * IMG + (size_t)((n & 63) * PATCH)];
        const float4 e = *reinterpret_cast<const float4*>(ebase + (size_t)t * CH);
        accW.x += m * e.x; accW.y += m * e.y; accW.z += m * e.z; accW.w += m * e.w;
        accS.x += e.x;     accS.y += e.y;     accS.z += e.z;     accS.w += e.w;
        if (is_q) {
            const float d = e.x * e.x + e.y * e.y + e.z * e.z + e.w * e.w;
            accA += m * d;
            accB += d;
        }
        accm += m;   // wave-uniform
    }

    // cross-wave reduce (all 4 waves cover the same 256 channels)
    __shared__ __align__(16) float ldsW[4][CH];
    __shared__ __align__(16) float ldsS[4][CH];
    __shared__ float ldsA[4], ldsB[4], ldsM[4];

    *reinterpret_cast<float4*>(&ldsW[w][cbase]) = accW;
    *reinterpret_cast<float4*>(&ldsS[w][cbase]) = accS;
    if (is_q) {
        accA = wave_reduce_sum(accA);
        accB = wave_reduce_sum(accB);
    }
    if (lane == 0) { ldsA[w] = accA; ldsB[w] = accB; ldsM[w] = accm; }
    __syncthreads();

    float* p = ws + (size_t)bid * PART_STRIDE;
    const int c = tid;
    p[c]      = ldsW[0][c] + ldsW[1][c] + ldsW[2][c] + ldsW[3][c];
    p[CH + c] = ldsS[0][c] + ldsS[1][c] + ldsS[2][c] + ldsS[3][c];
    if (tid == 0) {
        p[512] = ldsM[0] + ldsM[1] + ldsM[2] + ldsM[3];
        p[513] = is_q ? (ldsA[0] + ldsA[1] + ldsA[2] + ldsA[3]) : 0.f;
        p[514] = is_q ? (ldsB[0] + ldsB[1] + ldsB[2] + ldsB[3]) : 0.f;
    }
}

__global__ __launch_bounds__(256) void finalize_kernel(
    const float* __restrict__ ws, float* __restrict__ out)
{
    const int b   = blockIdx.x;     // one block per batch element
    const int tid = threadIdx.x;    // one thread per channel

    float pn = 0.f, se = 0.f, uu = 0.f, vv = 0.f;
    #pragma unroll 8
    for (int k = 0; k < CHUNKS; ++k) {
        const float* pe = ws + (size_t)(b * CHUNKS + k) * PART_STRIDE;
        const float* pq = pe + (size_t)(BATCH * CHUNKS) * PART_STRIDE;
        pn += pe[tid];      se += pe[CH + tid];
        uu += pq[tid];      vv += pq[CH + tid];
    }

    // batch scalars: chunk k handled by lane k of wave 0
    __shared__ float sc[4];   // cnt_ep, A, Bq, npos
    if (tid < 64) {
        float c0 = 0.f, a0 = 0.f, b0 = 0.f, n0 = 0.f;
        if (tid < CHUNKS) {
            const float* pe = ws + (size_t)(b * CHUNKS + tid) * PART_STRIDE;
            const float* pq = pe + (size_t)(BATCH * CHUNKS) * PART_STRIDE;
            c0 = pe[512]; a0 = pq[513]; b0 = pq[514]; n0 = pq[512];
        }
        c0 = wave_reduce_sum(c0); a0 = wave_reduce_sum(a0);
        b0 = wave_reduce_sum(b0); n0 = wave_reduce_sum(n0);
        if (tid == 0) { sc[0] = c0; sc[1] = a0; sc[2] = b0; sc[3] = n0; }
    }
    __syncthreads();

    const float cnt = sc[0], A = sc[1], Bv = sc[2], np = sc[3];
    const float pc = pn / (cnt + 0.1f);
    const float nc = (se - pn) / (((float)NTOK - cnt) + 0.1f);

    float4 t;
    t.x = uu * pc;          // u . p
    t.y = (vv - uu) * nc;   // (v-u) . n
    t.z = pc * pc;          // ||p||^2
    t.w = nc * nc;          // ||n||^2

    __shared__ float4 red[256];
    red[tid] = t;
    __syncthreads();
    for (int s = 128; s > 0; s >>= 1) {
        if (tid < s) {
            red[tid].x += red[tid + s].x;
            red[tid].y += red[tid + s].y;
            red[tid].z += red[tid + s].z;
            red[tid].w += red[tid + s].w;
        }
        __syncthreads();
    }

    if (tid == 0) {
        const float nn = (float)NTOK - np;
        const float pos_term = A - 2.f * red[0].x + np * red[0].z;
        const float neg_term = (Bv - A) - 2.f * red[0].y + nn * red[0].w;
        const float pos_loss = (np > 0.f) ? pos_term / (fmaxf(np, 1.f) * (float)CH) : 0.f;
        const float neg_loss = (nn > 0.f) ? neg_term / (fmaxf(nn, 1.f) * (float)CH) : 0.f;
        const float inv_b = 1.f / (float)BATCH;
        atomicAdd(&out[0], (pos_loss + neg_loss) * inv_b);
        atomicAdd(&out[1], pos_loss * inv_b);
        atomicAdd(&out[2], neg_loss * inv_b);
    }
}

extern "C" void kernel_launch(void* const* d_in, const int* in_sizes, int n_in,
                              void* d_out, int out_size, void* d_ws, size_t ws_size,
                              hipStream_t stream) {
    const float* ep_e = (const float*)d_in[0];  // ep_mask_embed (8,4096,256)
    const float* ep_m = (const float*)d_in[1];  // ep_mask (8,1,1024,1024)
    const float* q_e  = (const float*)d_in[2];  // query_mask_embed
    const float* q_m  = (const float*)d_in[3];  // query_mask
    float* out = (float*)d_out;
    float* ws  = (float*)d_ws;

    stats_kernel<<<NBLK_STATS, 256, 0, stream>>>(ep_e, ep_m, q_e, q_m, ws, out);
    finalize_kernel<<<BATCH, 256, 0, stream>>>(ws, out);
}